// Round 4
// baseline (272.104 us; speedup 1.0000x reference)
//
#include <hip/hip_runtime.h>
#include <cstdint>
#include <cstddef>

#define N_ROWS   65536
#define D_IN     512
#define D_OUT    512
#define N_WORDS  256
#define N_BOOKS  8
#define TAU      5.0f
#define LOG2E    1.44269504088896340736f

typedef __attribute__((ext_vector_type(8))) short short8;
typedef __attribute__((ext_vector_type(4))) float f32x4;

// hardware bf16 convert (RNE) — native __bf16 lets the compiler pair into v_cvt_pk_bf16_f32
__device__ __forceinline__ unsigned short f2bf(float f) {
    __bf16 h = (__bf16)f;
    return __builtin_bit_cast(unsigned short, h);
}
__device__ __forceinline__ float bf2f(unsigned short h) {
    unsigned u = ((unsigned)h) << 16;
    return __builtin_bit_cast(float, u);
}

// ============ Kernel 0: pre-pack codebook into MFMA fragment order ============
// packA [b][ks(2)][mf(16)][lane(64)][i(8)] : A-frag for xc GEMM (row=m, k=feature)
//   lane l, elem i -> Cb[(l&15)+16*mf][(l>>4)*8+i+32*ks]
// packB [b][ks2(8)][n2(4)][lane(64)][i(8)] : B-frag for Z GEMM (B[m][l]=Cb[m][l])
//   lane l, elem i -> Cb[(l>>4)*8+i+32*ks2][(l&15)+16*n2]
// nc2  [b][m] = -TAU*LOG2E * sum_l bf16(Cb[m][l])^2   (log2-domain bias)
__global__ __launch_bounds__(256) void prep_codebook(
        const float* __restrict__ C, unsigned short* __restrict__ packA,
        unsigned short* __restrict__ packB, float* __restrict__ nc2) {
    const int gid = blockIdx.x * 256 + threadIdx.x;
    if (gid < 131072) {                       // packA
        const int i  = gid & 7;
        const int l  = (gid >> 3) & 63;
        const int mf = (gid >> 9) & 15;
        const int ks = (gid >> 13) & 1;
        const int b  = gid >> 14;
        const int row = (l & 15) + 16 * mf;                   // m
        const int col = b * 64 + (l >> 4) * 8 + i + 32 * ks;  // k within C row
        packA[gid] = f2bf(C[(size_t)row * D_IN + col]);
    } else if (gid < 262144) {                // packB
        const int g   = gid - 131072;
        const int i   = g & 7;
        const int l   = (g >> 3) & 63;
        const int n2  = (g >> 9) & 3;
        const int ks2 = (g >> 11) & 7;
        const int b   = g >> 14;
        const int m   = (l >> 4) * 8 + i + 32 * ks2;
        const int col = b * 64 + (l & 15) + 16 * n2;
        packB[g] = f2bf(C[(size_t)m * D_IN + col]);
    } else if (gid < 264192) {                // nc2
        const int t = gid - 262144;
        const int b = t >> 8, m = t & 255;
        const float* cp = C + (size_t)m * D_IN + b * 64;
        float s = 0.f;
        for (int l = 0; l < 64; ++l) {
            const float v = bf2f(f2bf(cp[l]));
            s = fmaf(v, v, s);
        }
        nc2[t] = -TAU * LOG2E * s;
    }
}

// ============ Kernel 1: X = x @ W^T + b  (bf16 MFMA, fp32 accum) ============
#define ASTR 40   // padded LDS row stride in bf16 elems (80 B: 2-way banks = free)

__global__ __launch_bounds__(256) void gemm_fc(
        const float* __restrict__ x, const float* __restrict__ W,
        const float* __restrict__ bias, float* __restrict__ X) {
    __shared__ unsigned short Asm[128 * ASTR];
    __shared__ unsigned short Bsm[128 * ASTR];

    const int tid = threadIdx.x;
    const int bid = blockIdx.x;
    const int swz = (bid & 7) * 256 + (bid >> 3);   // XCD swizzle (2048 % 8 == 0)
    const int bm = swz >> 2, bn = swz & 3;
    const int n0 = bm * 128, c0 = bn * 128;
    const int lane = tid & 63, w = tid >> 6;
    const int wr = w >> 1, wc = w & 1;
    const int lo = lane & 15, hi = lane >> 4;

    const int sr = tid >> 1;            // staging row 0..127 (2 threads/row)
    const int sf = (tid & 1) << 4;      // k-offset 0 or 16

    f32x4 acc[4][4];
    #pragma unroll
    for (int i = 0; i < 4; ++i)
        #pragma unroll
        for (int j = 0; j < 4; ++j) acc[i][j] = (f32x4){0.f, 0.f, 0.f, 0.f};

    // register double-buffer of the staging loads
    float4 ra[4], rb[4];
    {
        const float* xa = &x[(size_t)(n0 + sr) * D_IN + sf];
        const float* wb = &W[(size_t)(c0 + sr) * D_IN + sf];
        #pragma unroll
        for (int q = 0; q < 4; ++q) {
            ra[q] = *reinterpret_cast<const float4*>(xa + q * 4);
            rb[q] = *reinterpret_cast<const float4*>(wb + q * 4);
        }
    }

    for (int k0 = 0; k0 < D_IN; k0 += 32) {
        #pragma unroll
        for (int q = 0; q < 4; ++q) {
            ushort4 pa, pb;
            pa.x = f2bf(ra[q].x); pa.y = f2bf(ra[q].y);
            pa.z = f2bf(ra[q].z); pa.w = f2bf(ra[q].w);
            pb.x = f2bf(rb[q].x); pb.y = f2bf(rb[q].y);
            pb.z = f2bf(rb[q].z); pb.w = f2bf(rb[q].w);
            *reinterpret_cast<ushort4*>(&Asm[sr * ASTR + sf + q * 4]) = pa;
            *reinterpret_cast<ushort4*>(&Bsm[sr * ASTR + sf + q * 4]) = pb;
        }
        if (k0 + 32 < D_IN) {
            const float* xa = &x[(size_t)(n0 + sr) * D_IN + k0 + 32 + sf];
            const float* wb = &W[(size_t)(c0 + sr) * D_IN + k0 + 32 + sf];
            #pragma unroll
            for (int q = 0; q < 4; ++q) {
                ra[q] = *reinterpret_cast<const float4*>(xa + q * 4);
                rb[q] = *reinterpret_cast<const float4*>(wb + q * 4);
            }
        }
        __syncthreads();
        short8 a[4], bb[4];
        #pragma unroll
        for (int fm = 0; fm < 4; ++fm)
            a[fm] = *reinterpret_cast<const short8*>(&Asm[(wr * 64 + fm * 16 + lo) * ASTR + hi * 8]);
        #pragma unroll
        for (int fn = 0; fn < 4; ++fn)
            bb[fn] = *reinterpret_cast<const short8*>(&Bsm[(wc * 64 + fn * 16 + lo) * ASTR + hi * 8]);
        #pragma unroll
        for (int fm = 0; fm < 4; ++fm)
            #pragma unroll
            for (int fn = 0; fn < 4; ++fn)
                acc[fm][fn] = __builtin_amdgcn_mfma_f32_16x16x32_bf16(
                    a[fm], bb[fn], acc[fm][fn], 0, 0, 0);
        __syncthreads();
    }

    #pragma unroll
    for (int fn = 0; fn < 4; ++fn) {
        const float bv = bias[c0 + wc * 64 + fn * 16 + lo];
        #pragma unroll
        for (int fm = 0; fm < 4; ++fm)
            #pragma unroll
            for (int j = 0; j < 4; ++j)
                X[(size_t)(n0 + wr * 64 + fm * 16 + hi * 4 + j) * D_OUT
                  + c0 + wc * 64 + fn * 16 + lo] = acc[fm][fn][j] + bv;
    }
}

// ============ Kernel 2: soft quantization head — barrier-free, per-wave ============
// Block = (book b, 64 rows); wave w owns rows n0+16w..+15 against ALL 256 codewords.
// xc = mfma(Cb, X^T): lane holds scores for x-row `lo`, m = 16*mf + 4*hi + j.
// Softmax fully in-lane (no max-sub needed: |logit| <= ~90 in exp2 domain, fp32-safe).
// Unnormalized bf16 p bounced through wave-private LDS to re-fragment for the Z GEMM.
// ZERO __syncthreads.
#define SSTR 264   // soft LDS row stride in bf16 elems

__global__ __launch_bounds__(256) void quant_head(
        const float* __restrict__ X, const unsigned short* __restrict__ packA,
        const unsigned short* __restrict__ packB, const float* __restrict__ nc2g,
        float* __restrict__ Z) {
    __shared__ __attribute__((aligned(16))) unsigned short soft[4][16][SSTR];

    const int tid  = threadIdx.x;
    const int b    = blockIdx.x & 7;
    const int n0   = (blockIdx.x >> 3) * 64;
    const int lane = tid & 63;
    const int w    = tid >> 6;
    const int lo = lane & 15, hi = lane >> 4;
    const int row = n0 + w * 16 + lo;          // this lane's x-row

    // ---- X row slice -> bf16 B-frags (col = x-row, k = feature) ----
    short8 xf[2];
    {
        const float* xp = X + (size_t)row * D_OUT + b * 64 + hi * 8;
        #pragma unroll
        for (int ks = 0; ks < 2; ++ks) {
            const float4 v0 = *reinterpret_cast<const float4*>(xp + ks * 32);
            const float4 v1 = *reinterpret_cast<const float4*>(xp + ks * 32 + 4);
            short8 t;
            t[0] = (short)f2bf(v0.x); t[1] = (short)f2bf(v0.y);
            t[2] = (short)f2bf(v0.z); t[3] = (short)f2bf(v0.w);
            t[4] = (short)f2bf(v1.x); t[5] = (short)f2bf(v1.y);
            t[6] = (short)f2bf(v1.z); t[7] = (short)f2bf(v1.w);
            xf[ks] = t;
        }
    }

    // ---- xc MFMA: all 256 m in this wave's accumulators ----
    f32x4 acc[16];
    #pragma unroll
    for (int mf = 0; mf < 16; ++mf) acc[mf] = (f32x4){0.f, 0.f, 0.f, 0.f};

    #pragma unroll
    for (int ks = 0; ks < 2; ++ks)
        #pragma unroll
        for (int mf = 0; mf < 16; ++mf) {
            const short8 cfr = *reinterpret_cast<const short8*>(
                packA + ((size_t)(((b * 2 + ks) * 16) + mf) * 64 + lane) * 8);
            acc[mf] = __builtin_amdgcn_mfma_f32_16x16x32_bf16(cfr, xf[ks], acc[mf], 0, 0, 0);
        }

    // ---- logits (log2 domain) -> unnormalized p -> bf16 soft LDS; in-lane sum ----
    const float S2 = 2.0f * TAU * LOG2E;
    float s = 0.f;
    #pragma unroll
    for (int mf = 0; mf < 16; ++mf) {
        const f32x4 nv = *reinterpret_cast<const f32x4*>(nc2g + b * 256 + mf * 16 + hi * 4);
        const float p0 = exp2f(fmaf(acc[mf][0], S2, nv[0]));
        const float p1 = exp2f(fmaf(acc[mf][1], S2, nv[1]));
        const float p2 = exp2f(fmaf(acc[mf][2], S2, nv[2]));
        const float p3 = exp2f(fmaf(acc[mf][3], S2, nv[3]));
        s += (p0 + p1) + (p2 + p3);
        ushort4 us;
        us.x = f2bf(p0); us.y = f2bf(p1); us.z = f2bf(p2); us.w = f2bf(p3);
        *reinterpret_cast<ushort4*>(&soft[w][lo][mf * 16 + hi * 4]) = us;
    }
    s += __shfl_xor(s, 16, 64);
    s += __shfl_xor(s, 32, 64);
    const float inv = 1.0f / s;                // full 256-sum for row `lo`

    // ---- Z = soft @ Cb (wave-private A, global packB) ----
    f32x4 acc2[4];
    #pragma unroll
    for (int n2 = 0; n2 < 4; ++n2) acc2[n2] = (f32x4){0.f, 0.f, 0.f, 0.f};
    #pragma unroll
    for (int ks2 = 0; ks2 < 8; ++ks2) {
        const short8 pa = *reinterpret_cast<const short8*>(
            &soft[w][lo][ks2 * 32 + hi * 8]);
        #pragma unroll
        for (int n2 = 0; n2 < 4; ++n2) {
            const short8 bv = *reinterpret_cast<const short8*>(
                packB + ((size_t)(((b * 8 + ks2) * 4) + n2) * 64 + lane) * 8);
            acc2[n2] = __builtin_amdgcn_mfma_f32_16x16x32_bf16(pa, bv, acc2[n2], 0, 0, 0);
        }
    }

    // ---- scale by 1/sum (rows live at hi*4+j here) and store ----
    float invr[4];
    #pragma unroll
    for (int j = 0; j < 4; ++j) invr[j] = __shfl(inv, hi * 4 + j, 64);
    #pragma unroll
    for (int n2 = 0; n2 < 4; ++n2)
        #pragma unroll
        for (int j = 0; j < 4; ++j)
            Z[(size_t)(n0 + w * 16 + hi * 4 + j) * D_OUT + b * 64 + n2 * 16 + lo]
                = acc2[n2][j] * invr[j];
}

// ============ launch ============
extern "C" void kernel_launch(void* const* d_in, const int* in_sizes, int n_in,
                              void* d_out, int out_size, void* d_ws, size_t ws_size,
                              hipStream_t stream) {
    const float* x = (const float*)d_in[0];
    const float* W = (const float*)d_in[1];
    const float* b = (const float*)d_in[2];
    const float* C = (const float*)d_in[3];

    float* X = (float*)d_out;                      // output 0: [65536, 512]
    float* Z = X + (size_t)N_ROWS * D_OUT;         // output 1: [65536, 512]

    unsigned short* packA = (unsigned short*)d_ws;          // 131072 bf16 = 256 KB
    unsigned short* packB = packA + 131072;                 // 131072 bf16 = 256 KB
    float*          nc2g  = (float*)(packB + 131072);       // 2048 fp32  =   8 KB

    prep_codebook<<<dim3(1032), dim3(256), 0, stream>>>(C, packA, packB, nc2g);
    gemm_fc<<<dim3(2048), dim3(256), 0, stream>>>(x, W, b, X);
    quant_head<<<dim3(N_BOOKS * (N_ROWS / 64)), dim3(256), 0, stream>>>(X, packA, packB, nc2g, Z);
}

// Round 5
// 217.768 us; speedup vs baseline: 1.2495x; 1.2495x over previous
//
#include <hip/hip_runtime.h>
#include <cstdint>
#include <cstddef>

#define N_ROWS   65536
#define D_IN     512
#define D_OUT    512
#define N_WORDS  256
#define N_BOOKS  8
#define TAU      5.0f
#define LOG2E    1.44269504088896340736f

typedef __attribute__((ext_vector_type(8))) short short8;
typedef __attribute__((ext_vector_type(4))) float f32x4;

// hardware bf16 convert (RNE) — native __bf16 lets the compiler pair into v_cvt_pk_bf16_f32
__device__ __forceinline__ unsigned short f2bf(float f) {
    __bf16 h = (__bf16)f;
    return __builtin_bit_cast(unsigned short, h);
}
__device__ __forceinline__ float bf2f(unsigned short h) {
    unsigned u = ((unsigned)h) << 16;
    return __builtin_bit_cast(float, u);
}

// ============ Kernel 0: pre-pack codebook into MFMA fragment order ============
// packA [b][ks(2)][mf(16)][lane(64)][i(8)] : A-frag for xc GEMM (row=m, k=feature)
//   lane l, elem i -> Cb[(l&15)+16*mf][(l>>4)*8+i+32*ks]
// packB [b][ks2(8)][n2(4)][lane(64)][i(8)] : B-frag for Z GEMM (B[m][l]=Cb[m][l])
//   lane l, elem i -> Cb[(l>>4)*8+i+32*ks2][(l&15)+16*n2]
// nc2  [b][m] = -TAU*LOG2E * sum_l bf16(Cb[m][l])^2   (log2-domain bias)
__global__ __launch_bounds__(256) void prep_codebook(
        const float* __restrict__ C, unsigned short* __restrict__ packA,
        unsigned short* __restrict__ packB, float* __restrict__ nc2) {
    const int gid = blockIdx.x * 256 + threadIdx.x;
    if (gid < 131072) {                       // packA
        const int i  = gid & 7;
        const int l  = (gid >> 3) & 63;
        const int mf = (gid >> 9) & 15;
        const int ks = (gid >> 13) & 1;
        const int b  = gid >> 14;
        const int row = (l & 15) + 16 * mf;                   // m
        const int col = b * 64 + (l >> 4) * 8 + i + 32 * ks;  // k within C row
        packA[gid] = f2bf(C[(size_t)row * D_IN + col]);
    } else if (gid < 262144) {                // packB
        const int g   = gid - 131072;
        const int i   = g & 7;
        const int l   = (g >> 3) & 63;
        const int n2  = (g >> 9) & 3;
        const int ks2 = (g >> 11) & 7;
        const int b   = g >> 14;
        const int m   = (l >> 4) * 8 + i + 32 * ks2;
        const int col = b * 64 + (l & 15) + 16 * n2;
        packB[g] = f2bf(C[(size_t)m * D_IN + col]);
    } else if (gid < 264192) {                // nc2
        const int t = gid - 262144;
        const int b = t >> 8, m = t & 255;
        const float* cp = C + (size_t)m * D_IN + b * 64;
        float s = 0.f;
        for (int l = 0; l < 64; ++l) {
            const float v = bf2f(f2bf(cp[l]));
            s = fmaf(v, v, s);
        }
        nc2[t] = -TAU * LOG2E * s;
    }
}

// ============ Kernel 1: X = x @ W^T + b  (bf16 MFMA, fp32 accum) ============
#define ASTR 40   // padded LDS row stride in bf16 elems (80 B: 2-way banks = free)

__global__ __launch_bounds__(256) void gemm_fc(
        const float* __restrict__ x, const float* __restrict__ W,
        const float* __restrict__ bias, float* __restrict__ X) {
    __shared__ unsigned short Asm[128 * ASTR];
    __shared__ unsigned short Bsm[128 * ASTR];

    const int tid = threadIdx.x;
    const int bid = blockIdx.x;
    const int swz = (bid & 7) * 256 + (bid >> 3);   // XCD swizzle (2048 % 8 == 0)
    const int bm = swz >> 2, bn = swz & 3;
    const int n0 = bm * 128, c0 = bn * 128;
    const int lane = tid & 63, w = tid >> 6;
    const int wr = w >> 1, wc = w & 1;
    const int lo = lane & 15, hi = lane >> 4;

    const int sr = tid >> 1;            // staging row 0..127 (2 threads/row)
    const int sf = (tid & 1) << 4;      // k-offset 0 or 16

    f32x4 acc[4][4];
    #pragma unroll
    for (int i = 0; i < 4; ++i)
        #pragma unroll
        for (int j = 0; j < 4; ++j) acc[i][j] = (f32x4){0.f, 0.f, 0.f, 0.f};

    // register double-buffer of the staging loads
    float4 ra[4], rb[4];
    {
        const float* xa = &x[(size_t)(n0 + sr) * D_IN + sf];
        const float* wb = &W[(size_t)(c0 + sr) * D_IN + sf];
        #pragma unroll
        for (int q = 0; q < 4; ++q) {
            ra[q] = *reinterpret_cast<const float4*>(xa + q * 4);
            rb[q] = *reinterpret_cast<const float4*>(wb + q * 4);
        }
    }

    for (int k0 = 0; k0 < D_IN; k0 += 32) {
        #pragma unroll
        for (int q = 0; q < 4; ++q) {
            ushort4 pa, pb;
            pa.x = f2bf(ra[q].x); pa.y = f2bf(ra[q].y);
            pa.z = f2bf(ra[q].z); pa.w = f2bf(ra[q].w);
            pb.x = f2bf(rb[q].x); pb.y = f2bf(rb[q].y);
            pb.z = f2bf(rb[q].z); pb.w = f2bf(rb[q].w);
            *reinterpret_cast<ushort4*>(&Asm[sr * ASTR + sf + q * 4]) = pa;
            *reinterpret_cast<ushort4*>(&Bsm[sr * ASTR + sf + q * 4]) = pb;
        }
        if (k0 + 32 < D_IN) {
            const float* xa = &x[(size_t)(n0 + sr) * D_IN + k0 + 32 + sf];
            const float* wb = &W[(size_t)(c0 + sr) * D_IN + k0 + 32 + sf];
            #pragma unroll
            for (int q = 0; q < 4; ++q) {
                ra[q] = *reinterpret_cast<const float4*>(xa + q * 4);
                rb[q] = *reinterpret_cast<const float4*>(wb + q * 4);
            }
        }
        __syncthreads();
        short8 a[4], bb[4];
        #pragma unroll
        for (int fm = 0; fm < 4; ++fm)
            a[fm] = *reinterpret_cast<const short8*>(&Asm[(wr * 64 + fm * 16 + lo) * ASTR + hi * 8]);
        #pragma unroll
        for (int fn = 0; fn < 4; ++fn)
            bb[fn] = *reinterpret_cast<const short8*>(&Bsm[(wc * 64 + fn * 16 + lo) * ASTR + hi * 8]);
        #pragma unroll
        for (int fm = 0; fm < 4; ++fm)
            #pragma unroll
            for (int fn = 0; fn < 4; ++fn)
                acc[fm][fn] = __builtin_amdgcn_mfma_f32_16x16x32_bf16(
                    a[fm], bb[fn], acc[fm][fn], 0, 0, 0);
        __syncthreads();
    }

    #pragma unroll
    for (int fn = 0; fn < 4; ++fn) {
        const float bv = bias[c0 + wc * 64 + fn * 16 + lo];
        #pragma unroll
        for (int fm = 0; fm < 4; ++fm)
            #pragma unroll
            for (int j = 0; j < 4; ++j)
                X[(size_t)(n0 + wr * 64 + fm * 16 + hi * 4 + j) * D_OUT
                  + c0 + wc * 64 + fn * 16 + lo] = acc[fm][fn][j] + bv;
    }
}

// ============ Kernel 2: soft quantization head — LDS codebook, 8 waves ============
// Block = (book b, 256 rows), 512 threads. Codebook frags (packA 32K + packB 32K)
// staged in LDS once, then each wave independently handles 32 rows x all 256 m:
// two 16-row halves share every cfr ds_read (2 MFMAs per read), X frags register-
// resident (16 MFMAs per load). Wave-private soft buffer (8.4 KB) re-fragments the
// unnormalized bf16 p for the Z GEMM; one __syncthreads total (after staging).
#define SSTR 264   // soft row stride in bf16 elems (528 B, 16B-aligned reads)

__global__ __launch_bounds__(512, 2) void quant_head(
        const float* __restrict__ X, const unsigned short* __restrict__ packA,
        const unsigned short* __restrict__ packB, const float* __restrict__ nc2g,
        float* __restrict__ Z) {
    extern __shared__ __attribute__((aligned(16))) char smem[];
    unsigned short* cbA  = reinterpret_cast<unsigned short*>(smem);           // 16384 ush
    unsigned short* cbB  = cbA + 16384;                                       // 16384 ush
    float*          nc2s = reinterpret_cast<float*>(cbB + 16384);             // 256 f32
    unsigned short* soft = reinterpret_cast<unsigned short*>(nc2s + 256);     // 8*16*SSTR

    const int tid  = threadIdx.x;
    const int b    = blockIdx.x & 7;
    const int n0   = (blockIdx.x >> 3) * 256;
    const int lane = tid & 63;
    const int w    = tid >> 6;
    const int lo = lane & 15, hi = lane >> 4;
    unsigned short* soft_w = soft + w * (16 * SSTR);

    // ---- issue X loads early (independent of LDS staging) ----
    float4 rx[2][4];   // [half][4 float4 = 16 floats of this row's 64-col slice]
    #pragma unroll
    for (int h = 0; h < 2; ++h) {
        const float* xp = X + (size_t)(n0 + w * 32 + h * 16 + lo) * D_OUT + b * 64 + hi * 8;
        rx[h][0] = *reinterpret_cast<const float4*>(xp);
        rx[h][1] = *reinterpret_cast<const float4*>(xp + 4);
        rx[h][2] = *reinterpret_cast<const float4*>(xp + 32);
        rx[h][3] = *reinterpret_cast<const float4*>(xp + 36);
    }

    // ---- stage codebook frags + nc2 into LDS (once per block) ----
    {
        const float4* gA = reinterpret_cast<const float4*>(packA + (size_t)b * 16384);
        const float4* gB = reinterpret_cast<const float4*>(packB + (size_t)b * 16384);
        float4* sA = reinterpret_cast<float4*>(cbA);
        float4* sB = reinterpret_cast<float4*>(cbB);
        #pragma unroll
        for (int it = 0; it < 4; ++it) {
            const int idx = it * 512 + tid;    // 0..2047
            sA[idx] = gA[idx];
            sB[idx] = gB[idx];
        }
        if (tid < 256) nc2s[tid] = nc2g[b * 256 + tid];
    }

    // ---- convert X to bf16 MFMA B-frags while staging lands ----
    short8 xf[2][2];   // [half][ks]
    #pragma unroll
    for (int h = 0; h < 2; ++h)
        #pragma unroll
        for (int ks = 0; ks < 2; ++ks) {
            const float4 v0 = rx[h][ks * 2];
            const float4 v1 = rx[h][ks * 2 + 1];
            short8 t;
            t[0] = (short)f2bf(v0.x); t[1] = (short)f2bf(v0.y);
            t[2] = (short)f2bf(v0.z); t[3] = (short)f2bf(v0.w);
            t[4] = (short)f2bf(v1.x); t[5] = (short)f2bf(v1.y);
            t[6] = (short)f2bf(v1.z); t[7] = (short)f2bf(v1.w);
            xf[h][ks] = t;
        }

    __syncthreads();   // codebook + nc2 staged

    // ---- xc MFMA: 32 rows x 256 m, every cfr read feeds 2 MFMAs ----
    f32x4 acc[2][16];  // [half][mf]
    #pragma unroll
    for (int h = 0; h < 2; ++h)
        #pragma unroll
        for (int mf = 0; mf < 16; ++mf) acc[h][mf] = (f32x4){0.f, 0.f, 0.f, 0.f};

    #pragma unroll
    for (int ks = 0; ks < 2; ++ks)
        #pragma unroll
        for (int mf = 0; mf < 16; ++mf) {
            const short8 cfr = *reinterpret_cast<const short8*>(
                &cbA[((ks * 16 + mf) * 64 + lane) * 8]);
            acc[0][mf] = __builtin_amdgcn_mfma_f32_16x16x32_bf16(cfr, xf[0][ks], acc[0][mf], 0, 0, 0);
            acc[1][mf] = __builtin_amdgcn_mfma_f32_16x16x32_bf16(cfr, xf[1][ks], acc[1][mf], 0, 0, 0);
        }

    // ---- per half: softmax (in-lane, exp2 domain, unnormalized) + Z GEMM ----
    const float S2 = 2.0f * TAU * LOG2E;
    #pragma unroll
    for (int h = 0; h < 2; ++h) {
        float s = 0.f;
        #pragma unroll
        for (int mf = 0; mf < 16; ++mf) {
            const f32x4 nv = *reinterpret_cast<const f32x4*>(&nc2s[mf * 16 + hi * 4]);
            const float p0 = exp2f(fmaf(acc[h][mf][0], S2, nv[0]));
            const float p1 = exp2f(fmaf(acc[h][mf][1], S2, nv[1]));
            const float p2 = exp2f(fmaf(acc[h][mf][2], S2, nv[2]));
            const float p3 = exp2f(fmaf(acc[h][mf][3], S2, nv[3]));
            s += (p0 + p1) + (p2 + p3);
            ushort4 us;
            us.x = f2bf(p0); us.y = f2bf(p1); us.z = f2bf(p2); us.w = f2bf(p3);
            *reinterpret_cast<ushort4*>(&soft_w[lo * SSTR + mf * 16 + hi * 4]) = us;
        }
        s += __shfl_xor(s, 16, 64);
        s += __shfl_xor(s, 32, 64);
        const float inv = 1.0f / s;         // full 256-sum for row `lo` of this half

        f32x4 acc2[4];
        #pragma unroll
        for (int n2 = 0; n2 < 4; ++n2) acc2[n2] = (f32x4){0.f, 0.f, 0.f, 0.f};
        #pragma unroll
        for (int ks2 = 0; ks2 < 8; ++ks2) {
            const short8 pa = *reinterpret_cast<const short8*>(
                &soft_w[lo * SSTR + ks2 * 32 + hi * 8]);
            #pragma unroll
            for (int n2 = 0; n2 < 4; ++n2) {
                const short8 bv = *reinterpret_cast<const short8*>(
                    &cbB[((ks2 * 4 + n2) * 64 + lane) * 8]);
                acc2[n2] = __builtin_amdgcn_mfma_f32_16x16x32_bf16(pa, bv, acc2[n2], 0, 0, 0);
            }
        }

        float invr[4];
        #pragma unroll
        for (int j = 0; j < 4; ++j) invr[j] = __shfl(inv, hi * 4 + j, 64);
        #pragma unroll
        for (int n2 = 0; n2 < 4; ++n2)
            #pragma unroll
            for (int j = 0; j < 4; ++j)
                Z[(size_t)(n0 + w * 32 + h * 16 + hi * 4 + j) * D_OUT + b * 64 + n2 * 16 + lo]
                    = acc2[n2][j] * invr[j];
    }
}

// ============ launch ============
extern "C" void kernel_launch(void* const* d_in, const int* in_sizes, int n_in,
                              void* d_out, int out_size, void* d_ws, size_t ws_size,
                              hipStream_t stream) {
    const float* x = (const float*)d_in[0];
    const float* W = (const float*)d_in[1];
    const float* b = (const float*)d_in[2];
    const float* C = (const float*)d_in[3];

    float* X = (float*)d_out;                      // output 0: [65536, 512]
    float* Z = X + (size_t)N_ROWS * D_OUT;         // output 1: [65536, 512]

    unsigned short* packA = (unsigned short*)d_ws;          // 131072 bf16 = 256 KB
    unsigned short* packB = packA + 131072;                 // 131072 bf16 = 256 KB
    float*          nc2g  = (float*)(packB + 131072);       // 2048 fp32  =   8 KB

    prep_codebook<<<dim3(1032), dim3(256), 0, stream>>>(C, packA, packB, nc2g);
    gemm_fc<<<dim3(2048), dim3(256), 0, stream>>>(x, W, b, X);

    const size_t lds_bytes = 16384 * 2 * sizeof(unsigned short)   // cbA + cbB
                           + 256 * sizeof(float)                  // nc2s
                           + 8 * 16 * SSTR * sizeof(unsigned short); // soft
    quant_head<<<dim3(N_BOOKS * (N_ROWS / 256)), dim3(512), lds_bytes, stream>>>(
        X, packA, packB, nc2g, Z);
}

// Round 6
// 182.557 us; speedup vs baseline: 1.4905x; 1.1929x over previous
//
#include <hip/hip_runtime.h>
#include <cstdint>
#include <cstddef>

#define N_ROWS   65536
#define D_IN     512
#define D_OUT    512
#define N_WORDS  256
#define N_BOOKS  8
#define TAU      5.0f
#define LOG2E    1.44269504088896340736f

typedef __attribute__((ext_vector_type(8))) short short8;
typedef __attribute__((ext_vector_type(4))) float f32x4;

// hardware bf16 convert (RNE) — native __bf16 lets the compiler pair into v_cvt_pk_bf16_f32
__device__ __forceinline__ unsigned short f2bf(float f) {
    __bf16 h = (__bf16)f;
    return __builtin_bit_cast(unsigned short, h);
}
__device__ __forceinline__ float bf2f(unsigned short h) {
    unsigned u = ((unsigned)h) << 16;
    return __builtin_bit_cast(float, u);
}

// ============ Kernel 0: pre-pack codebook + W into MFMA fragment order ============
// packA [b][ks(2)][mf(16)][lane(64)][i(8)] : A-frag for xc GEMM (row=m, k=feature)
//   lane l, elem i -> Cb[(l&15)+16*mf][(l>>4)*8+i+32*ks]
// packB [b][ks2(8)][n2(4)][lane(64)][i(8)] : B-frag for Z GEMM, m-order chosen to
//   match the NATIVE xc accumulator layout (no cross-lane re-fragmentation needed):
//   k-slot (hi=l>>4, i, ks2) -> m = 32*ks2 + 16*(i>>2) + 4*hi + (i&3)
// packW [bn(4)][kk(16)][cf(8)][lane(64)][i(8)] : B-frag for fc GEMM
//   lane l, elem i -> W[bn*128 + cf*16 + (l&15)][kk*32 + (l>>4)*8 + i]
// nc2  [b][m] = -TAU*LOG2E * sum_l bf16(Cb[m][l])^2   (log2-domain bias)
__global__ __launch_bounds__(256) void prep_codebook(
        const float* __restrict__ C, const float* __restrict__ W,
        unsigned short* __restrict__ packA, unsigned short* __restrict__ packB,
        unsigned short* __restrict__ packW, float* __restrict__ nc2) {
    const int gid = blockIdx.x * 256 + threadIdx.x;
    if (gid < 131072) {                       // packA
        const int i  = gid & 7;
        const int l  = (gid >> 3) & 63;
        const int mf = (gid >> 9) & 15;
        const int ks = (gid >> 13) & 1;
        const int b  = gid >> 14;
        const int row = (l & 15) + 16 * mf;                   // m
        const int col = b * 64 + (l >> 4) * 8 + i + 32 * ks;  // feature within C row
        packA[gid] = f2bf(C[(size_t)row * D_IN + col]);
    } else if (gid < 262144) {                // packB (acc-native m-order)
        const int g   = gid - 131072;
        const int i   = g & 7;
        const int l   = (g >> 3) & 63;
        const int n2  = (g >> 9) & 3;
        const int ks2 = (g >> 11) & 7;
        const int b   = g >> 14;
        const int m   = 32 * ks2 + 16 * (i >> 2) + 4 * (l >> 4) + (i & 3);
        const int col = b * 64 + n2 * 16 + (l & 15);
        packB[g] = f2bf(C[(size_t)m * D_IN + col]);
    } else if (gid < 524288) {                // packW
        const int h  = gid - 262144;
        const int i  = h & 7;
        const int l  = (h >> 3) & 63;
        const int cf = (h >> 9) & 7;
        const int kk = (h >> 12) & 15;
        const int bn = h >> 16;
        packW[h] = f2bf(W[(size_t)(bn * 128 + cf * 16 + (l & 15)) * D_IN
                          + kk * 32 + (l >> 4) * 8 + i]);
    } else if (gid < 526336) {                // nc2
        const int t = gid - 524288;
        const int b = t >> 8, m = t & 255;
        const float* cp = C + (size_t)m * D_IN + b * 64;
        float s = 0.f;
        for (int l = 0; l < 64; ++l) {
            const float v = bf2f(f2bf(cp[l]));
            s = fmaf(v, v, s);
        }
        nc2[t] = -TAU * LOG2E * s;
    }
}

// ============ Kernel 1: X = x @ W^T + b  (bf16 MFMA, W pre-packed) ============
#define ASTR 40   // padded LDS row stride in bf16 elems (80 B: 2-way banks = free)

__global__ __launch_bounds__(256) void gemm_fc(
        const float* __restrict__ x, const unsigned short* __restrict__ packW,
        const float* __restrict__ bias, float* __restrict__ X) {
    __shared__ unsigned short Asm[128 * ASTR];   // 10 KB — A staging only

    const int tid = threadIdx.x;
    const int bid = blockIdx.x;
    const int swz = (bid & 7) * 256 + (bid >> 3);   // XCD swizzle (2048 % 8 == 0)
    const int bm = swz >> 2, bn = swz & 3;
    const int n0 = bm * 128, c0 = bn * 128;
    const int lane = tid & 63, w = tid >> 6;
    const int wr = w >> 1, wc = w & 1;
    const int lo = lane & 15, hi = lane >> 4;

    const int sr = tid >> 1;            // staging row 0..127 (2 threads/row)
    const int sf = (tid & 1) << 4;      // k-offset 0 or 16

    f32x4 acc[4][4];
    #pragma unroll
    for (int i = 0; i < 4; ++i)
        #pragma unroll
        for (int j = 0; j < 4; ++j) acc[i][j] = (f32x4){0.f, 0.f, 0.f, 0.f};

    // register double-buffer of the A staging loads
    float4 ra[4];
    {
        const float* xa = &x[(size_t)(n0 + sr) * D_IN + sf];
        #pragma unroll
        for (int q = 0; q < 4; ++q)
            ra[q] = *reinterpret_cast<const float4*>(xa + q * 4);
    }

    for (int kk = 0; kk < 16; ++kk) {
        // convert + write current A tile to LDS
        #pragma unroll
        for (int q = 0; q < 4; ++q) {
            ushort4 pa;
            pa.x = f2bf(ra[q].x); pa.y = f2bf(ra[q].y);
            pa.z = f2bf(ra[q].z); pa.w = f2bf(ra[q].w);
            *reinterpret_cast<ushort4*>(&Asm[sr * ASTR + sf + q * 4]) = pa;
        }
        // prefetch next A tile (latency hidden by this tile's MFMAs)
        if (kk < 15) {
            const float* xa = &x[(size_t)(n0 + sr) * D_IN + (kk + 1) * 32 + sf];
            #pragma unroll
            for (int q = 0; q < 4; ++q)
                ra[q] = *reinterpret_cast<const float4*>(xa + q * 4);
        }
        // B frags from packW (L2/L1) — issued before the barrier so the
        // vmcnt(0) drain at the barrier covers their latency.
        short8 bb[4];
        {
            const unsigned short* wp = packW
                + ((size_t)((bn * 16 + kk) * 8 + wc * 4) * 64) * 8;
            #pragma unroll
            for (int fn = 0; fn < 4; ++fn)
                bb[fn] = *reinterpret_cast<const short8*>(wp + ((size_t)fn * 64 + lane) * 8);
        }
        __syncthreads();
        short8 a[4];
        #pragma unroll
        for (int fm = 0; fm < 4; ++fm)
            a[fm] = *reinterpret_cast<const short8*>(&Asm[(wr * 64 + fm * 16 + lo) * ASTR + hi * 8]);
        #pragma unroll
        for (int fm = 0; fm < 4; ++fm)
            #pragma unroll
            for (int fn = 0; fn < 4; ++fn)
                acc[fm][fn] = __builtin_amdgcn_mfma_f32_16x16x32_bf16(
                    a[fm], bb[fn], acc[fm][fn], 0, 0, 0);
        __syncthreads();
    }

    #pragma unroll
    for (int fn = 0; fn < 4; ++fn) {
        const float bv = bias[c0 + wc * 64 + fn * 16 + lo];
        #pragma unroll
        for (int fm = 0; fm < 4; ++fm)
            #pragma unroll
            for (int j = 0; j < 4; ++j)
                X[(size_t)(n0 + wr * 64 + fm * 16 + hi * 4 + j) * D_OUT
                  + c0 + wc * 64 + fn * 16 + lo] = acc[fm][fn][j] + bv;
    }
}

// ============ Kernel 2: soft quantization head — in-register pa, 2 blocks/CU ============
// Block = (book b, 128 rows), 512 threads; wave w owns rows n0+16w..+15 vs ALL 256 m.
// xc = mfma(Cb, X^T): lane (lo,hi) holds p[x-row lo][m = 16*mf + 4*hi + j].
// Z GEMM's A-operand (pa) is built IN-LANE from acc (packB's m-order matches the
// native acc layout) — no soft LDS, no shuffles. LDS = codebook only (66.5 KB).
__global__ __launch_bounds__(512, 4) void quant_head(
        const float* __restrict__ X, const unsigned short* __restrict__ packA,
        const unsigned short* __restrict__ packB, const float* __restrict__ nc2g,
        float* __restrict__ Z) {
    __shared__ __attribute__((aligned(16))) unsigned short cbA[16384];
    __shared__ __attribute__((aligned(16))) unsigned short cbB[16384];
    __shared__ float nc2s[256];

    const int tid  = threadIdx.x;
    const int b    = blockIdx.x & 7;          // book -> fixed XCD (codebook L2-pinned)
    const int n0   = (blockIdx.x >> 3) * 128;
    const int lane = tid & 63;
    const int w    = tid >> 6;
    const int lo = lane & 15, hi = lane >> 4;
    const int row = n0 + w * 16 + lo;

    // ---- X loads first (HBM latency starts earliest) ----
    const float* xp = X + (size_t)row * D_OUT + b * 64 + hi * 8;
    const float4 rx0 = *reinterpret_cast<const float4*>(xp);
    const float4 rx1 = *reinterpret_cast<const float4*>(xp + 4);
    const float4 rx2 = *reinterpret_cast<const float4*>(xp + 32);
    const float4 rx3 = *reinterpret_cast<const float4*>(xp + 36);

    // ---- stage codebook frags + nc2 into LDS ----
    {
        const float4* gA = reinterpret_cast<const float4*>(packA + (size_t)b * 16384);
        const float4* gB = reinterpret_cast<const float4*>(packB + (size_t)b * 16384);
        float4* sA = reinterpret_cast<float4*>(cbA);
        float4* sB = reinterpret_cast<float4*>(cbB);
        #pragma unroll
        for (int it = 0; it < 4; ++it) {
            sA[it * 512 + tid] = gA[it * 512 + tid];
            sB[it * 512 + tid] = gB[it * 512 + tid];
        }
        if (tid < 256) nc2s[tid] = nc2g[b * 256 + tid];
    }

    // ---- convert X to bf16 B-frags while staging lands ----
    short8 xf[2];
    {
        short8 t;
        t[0] = (short)f2bf(rx0.x); t[1] = (short)f2bf(rx0.y);
        t[2] = (short)f2bf(rx0.z); t[3] = (short)f2bf(rx0.w);
        t[4] = (short)f2bf(rx1.x); t[5] = (short)f2bf(rx1.y);
        t[6] = (short)f2bf(rx1.z); t[7] = (short)f2bf(rx1.w);
        xf[0] = t;
        t[0] = (short)f2bf(rx2.x); t[1] = (short)f2bf(rx2.y);
        t[2] = (short)f2bf(rx2.z); t[3] = (short)f2bf(rx2.w);
        t[4] = (short)f2bf(rx3.x); t[5] = (short)f2bf(rx3.y);
        t[6] = (short)f2bf(rx3.z); t[7] = (short)f2bf(rx3.w);
        xf[1] = t;
    }

    __syncthreads();   // codebook + nc2 staged

    // ---- xc MFMA: 16 rows x 256 m ----
    f32x4 acc[16];
    #pragma unroll
    for (int mf = 0; mf < 16; ++mf) acc[mf] = (f32x4){0.f, 0.f, 0.f, 0.f};
    #pragma unroll
    for (int ks = 0; ks < 2; ++ks)
        #pragma unroll
        for (int mf = 0; mf < 16; ++mf) {
            const short8 cfr = *reinterpret_cast<const short8*>(
                &cbA[((ks * 16 + mf) * 64 + lane) * 8]);
            acc[mf] = __builtin_amdgcn_mfma_f32_16x16x32_bf16(cfr, xf[ks], acc[mf], 0, 0, 0);
        }

    // ---- softmax (exp2 domain, in-lane, unnormalized p kept in acc) ----
    const float S2 = 2.0f * TAU * LOG2E;
    float s = 0.f;
    #pragma unroll
    for (int mf = 0; mf < 16; ++mf) {
        const f32x4 nv = *reinterpret_cast<const f32x4*>(&nc2s[mf * 16 + hi * 4]);
        const float p0 = exp2f(fmaf(acc[mf][0], S2, nv[0]));
        const float p1 = exp2f(fmaf(acc[mf][1], S2, nv[1]));
        const float p2 = exp2f(fmaf(acc[mf][2], S2, nv[2]));
        const float p3 = exp2f(fmaf(acc[mf][3], S2, nv[3]));
        acc[mf][0] = p0; acc[mf][1] = p1; acc[mf][2] = p2; acc[mf][3] = p3;
        s += (p0 + p1) + (p2 + p3);
    }
    s += __shfl_xor(s, 16, 64);
    s += __shfl_xor(s, 32, 64);
    const float inv = 1.0f / s;                // full 256-sum for x-row `lo`

    // ---- Z = p @ Cb : pa built in-lane (packB m-order == acc layout) ----
    f32x4 acc2[4];
    #pragma unroll
    for (int n2 = 0; n2 < 4; ++n2) acc2[n2] = (f32x4){0.f, 0.f, 0.f, 0.f};
    #pragma unroll
    for (int ks2 = 0; ks2 < 8; ++ks2) {
        short8 pa;
        pa[0] = (short)f2bf(acc[2 * ks2][0]);     pa[1] = (short)f2bf(acc[2 * ks2][1]);
        pa[2] = (short)f2bf(acc[2 * ks2][2]);     pa[3] = (short)f2bf(acc[2 * ks2][3]);
        pa[4] = (short)f2bf(acc[2 * ks2 + 1][0]); pa[5] = (short)f2bf(acc[2 * ks2 + 1][1]);
        pa[6] = (short)f2bf(acc[2 * ks2 + 1][2]); pa[7] = (short)f2bf(acc[2 * ks2 + 1][3]);
        #pragma unroll
        for (int n2 = 0; n2 < 4; ++n2) {
            const short8 bv = *reinterpret_cast<const short8*>(
                &cbB[((ks2 * 4 + n2) * 64 + lane) * 8]);
            acc2[n2] = __builtin_amdgcn_mfma_f32_16x16x32_bf16(pa, bv, acc2[n2], 0, 0, 0);
        }
    }

    float invr[4];
    #pragma unroll
    for (int j = 0; j < 4; ++j) invr[j] = __shfl(inv, hi * 4 + j, 64);
    #pragma unroll
    for (int n2 = 0; n2 < 4; ++n2)
        #pragma unroll
        for (int j = 0; j < 4; ++j)
            Z[(size_t)(n0 + w * 16 + hi * 4 + j) * D_OUT + b * 64 + n2 * 16 + lo]
                = acc2[n2][j] * invr[j];
}

// ============ launch ============
extern "C" void kernel_launch(void* const* d_in, const int* in_sizes, int n_in,
                              void* d_out, int out_size, void* d_ws, size_t ws_size,
                              hipStream_t stream) {
    const float* x = (const float*)d_in[0];
    const float* W = (const float*)d_in[1];
    const float* b = (const float*)d_in[2];
    const float* C = (const float*)d_in[3];

    float* X = (float*)d_out;                      // output 0: [65536, 512]
    float* Z = X + (size_t)N_ROWS * D_OUT;         // output 1: [65536, 512]

    unsigned short* packA = (unsigned short*)d_ws;          // 131072 bf16 = 256 KB
    unsigned short* packB = packA + 131072;                 // 131072 bf16 = 256 KB
    unsigned short* packW = packB + 131072;                 // 262144 bf16 = 512 KB
    float*          nc2g  = (float*)(packW + 262144);       // 2048 fp32  =   8 KB

    prep_codebook<<<dim3(2056), dim3(256), 0, stream>>>(C, W, packA, packB, packW, nc2g);
    gemm_fc<<<dim3(2048), dim3(256), 0, stream>>>(x, packW, b, X);
    quant_head<<<dim3(N_BOOKS * (N_ROWS / 128)), dim3(512), 0, stream>>>(
        X, packA, packB, nc2g, Z);
}